// Round 2
// baseline (6792.446 us; speedup 1.0000x reference)
//
#include <hip/hip_runtime.h>
#include <math.h>

#define NN   20000
#define EE   80000
#define ELP  100000   // EE + NN self loops
#define NGR  64
#define EMB  780
#define W3   2340

static inline int cdiv_i(long long a, long long b){ return (int)((a + b - 1) / b); }

typedef unsigned short ushortx;

__device__ __forceinline__ float b2f(unsigned short u){
    return __uint_as_float(((unsigned int)u) << 16);
}
__device__ __forceinline__ unsigned short f2b(float f){
    unsigned int u = __float_as_uint(f);
    u += 0x7FFFu + ((u >> 16) & 1u);   // round to nearest even
    return (unsigned short)(u >> 16);
}

// ---------------- utility kernels ----------------
__global__ void k_zero_f32(float* p, int n){
    int i = blockIdx.x*256 + threadIdx.x; if (i < n) p[i] = 0.f;
}
__global__ void k_zero_i32(int* p, int n){
    int i = blockIdx.x*256 + threadIdx.x; if (i < n) p[i] = 0;
}
__global__ void k_copy_i32(const int* __restrict__ s, int* __restrict__ d, int n){
    int i = blockIdx.x*256 + threadIdx.x; if (i < n) d[i] = s[i];
}
__global__ void k_castw(const float* __restrict__ W, ushortx* __restrict__ Wb, int n){
    int i = blockIdx.x*256 + threadIdx.x; if (i < n) Wb[i] = f2b(W[i]);
}

// ---------------- h0 = [x[:, :768], x[:,768:772] @ time_W + time_b] (bf16 out) ----------------
__global__ void k_build_h(const float* __restrict__ x, const float* __restrict__ tW,
                          const float* __restrict__ tb, ushortx* __restrict__ h){
    int idx = blockIdx.x*256 + threadIdx.x;
    if (idx >= NN*EMB) return;
    int n = idx / EMB, c = idx - n*EMB;
    const float* xr = x + (size_t)n*772;
    float v;
    if (c < 768) v = xr[c];
    else {
        int j = c - 768;
        v = tb[j] + xr[768]*tW[j] + xr[769]*tW[12+j] + xr[770]*tW[24+j] + xr[771]*tW[36+j];
    }
    h[idx] = f2b(v);
}

// ---------------- CSR build (dst-sorted incoming edges) ----------------
__global__ void k_deg(const int* __restrict__ ei, int* __restrict__ deg){
    int k = blockIdx.x*256 + threadIdx.x; if (k >= ELP) return;
    int d = (k < EE) ? ei[EE + k] : (k - EE);
    atomicAdd(&deg[d], 1);
}

__global__ __launch_bounds__(1024) void k_scan(const int* __restrict__ deg, int* __restrict__ rp){
    __shared__ int buf[1024];
    __shared__ int carry;
    int tid = threadIdx.x;
    if (tid == 0){ carry = 0; rp[0] = 0; }
    __syncthreads();
    for (int base = 0; base < NN; base += 1024){
        int i = base + tid;
        int v = (i < NN) ? deg[i] : 0;
        buf[tid] = v; __syncthreads();
        for (int off = 1; off < 1024; off <<= 1){
            int t = (tid >= off) ? buf[tid-off] : 0;
            __syncthreads();
            buf[tid] += t;
            __syncthreads();
        }
        int incl = buf[tid];
        int tot  = buf[1023];
        if (i < NN) rp[i+1] = carry + incl;
        __syncthreads();
        if (tid == 0) carry += tot;
        __syncthreads();
    }
}

__global__ void k_fill(const int* __restrict__ ei, int* __restrict__ cursor, int* __restrict__ csrc){
    int k = blockIdx.x*256 + threadIdx.x; if (k >= ELP) return;
    int s, d;
    if (k < EE){ s = ei[k]; d = ei[EE + k]; } else { s = k - EE; d = s; }
    int pos = atomicAdd(&cursor[d], 1);
    csrc[pos] = s;
}

// ------- bf16-storage GEMM: C[M,Nc] = A[M,K] @ B[K,Nc], K % 12 == 0, fp32 accumulate -------
__global__ __launch_bounds__(256) void k_gemm_bf16(const ushortx* __restrict__ A,
                                                   const ushortx* __restrict__ B,
                                                   ushortx* __restrict__ C,
                                                   int M, int K, int Nc){
    __shared__ float As[12][128];
    __shared__ float Bs[12][128];
    int tid = threadIdx.x;
    int tx = tid & 15, ty = tid >> 4;
    int m0 = blockIdx.y * 128, n0 = blockIdx.x * 128;

    float acc[8][8];
#pragma unroll
    for (int i = 0; i < 8; i++)
#pragma unroll
        for (int j = 0; j < 8; j++) acc[i][j] = 0.f;

    int lr  = tid >> 1;        // A tile row 0..127
    int lc0 = (tid & 1) * 6;   // A tile k-offset 0 or 6
    int bc  = tid & 127;       // B tile col 0..127
    int bk0 = (tid >> 7) * 6;  // B tile k-offset 0 or 6
    int arow = m0 + lr;
    int bcol = n0 + bc;

    for (int kk = 0; kk < K; kk += 12){
        float av[6], bv[6];
        if (arow < M){
            const ushortx* ap = A + (size_t)arow*K + kk + lc0;
            ushort2 t0 = *(const ushort2*)ap;
            ushort2 t1 = *(const ushort2*)(ap+2);
            ushort2 t2 = *(const ushort2*)(ap+4);
            av[0]=b2f(t0.x); av[1]=b2f(t0.y); av[2]=b2f(t1.x);
            av[3]=b2f(t1.y); av[4]=b2f(t2.x); av[5]=b2f(t2.y);
        } else {
#pragma unroll
            for (int i = 0; i < 6; i++) av[i] = 0.f;
        }
#pragma unroll
        for (int i = 0; i < 6; i++)
            bv[i] = (bcol < Nc) ? b2f(B[(size_t)(kk + bk0 + i)*Nc + bcol]) : 0.f;

        __syncthreads();
#pragma unroll
        for (int i = 0; i < 6; i++) As[lc0 + i][lr] = av[i];
#pragma unroll
        for (int i = 0; i < 6; i++) Bs[bk0 + i][bc] = bv[i];
        __syncthreads();

#pragma unroll
        for (int k = 0; k < 12; k++){
            float4 a0 = *(const float4*)&As[k][ty*8];
            float4 a1 = *(const float4*)&As[k][ty*8 + 4];
            float4 b0 = *(const float4*)&Bs[k][tx*8];
            float4 b1 = *(const float4*)&Bs[k][tx*8 + 4];
            float a[8] = {a0.x,a0.y,a0.z,a0.w,a1.x,a1.y,a1.z,a1.w};
            float b[8] = {b0.x,b0.y,b0.z,b0.w,b1.x,b1.y,b1.z,b1.w};
#pragma unroll
            for (int i = 0; i < 8; i++)
#pragma unroll
                for (int j = 0; j < 8; j++)
                    acc[i][j] += a[i]*b[j];
        }
    }

#pragma unroll
    for (int i = 0; i < 8; i++){
        int row = m0 + ty*8 + i;
        if (row < M){
            ushortx* cp = C + (size_t)row*Nc + n0 + tx*8;
            int col = n0 + tx*8;
            if (col < Nc){
                ushort4 o0; o0.x=f2b(acc[i][0]); o0.y=f2b(acc[i][1]); o0.z=f2b(acc[i][2]); o0.w=f2b(acc[i][3]);
                *(ushort4*)cp = o0;
            }
            if (col + 4 < Nc){
                ushort4 o1; o1.x=f2b(acc[i][4]); o1.y=f2b(acc[i][5]); o1.z=f2b(acc[i][6]); o1.w=f2b(acc[i][7]);
                *(ushort4*)(cp+4) = o1;
            }
        }
    }
}

// ---------------- attention coefficients a_s[n,h], a_d[n,h] ----------------
__global__ void k_att(const ushortx* __restrict__ hp, const float* __restrict__ asrc,
                      const float* __restrict__ adst, float* __restrict__ a_s,
                      float* __restrict__ a_d, int H){
    int n = blockIdx.x;
    int wv = threadIdx.x >> 6, lane = threadIdx.x & 63;
    const ushortx* row = hp + (size_t)n*H*EMB + (size_t)wv*EMB;
    const float* pa = asrc + wv*EMB;
    const float* pd = adst + wv*EMB;
    float s = 0.f, d = 0.f;
    for (int c = lane; c < EMB; c += 64){ float v = b2f(row[c]); s += v*pa[c]; d += v*pd[c]; }
#pragma unroll
    for (int off = 32; off; off >>= 1){ s += __shfl_xor(s, off); d += __shfl_xor(d, off); }
    if (lane == 0){ a_s[n*H + wv] = s; a_d[n*H + wv] = d; }
}

// ---------------- per-dst softmax + aggregation + bias + tanh ----------------
__global__ __launch_bounds__(256) void k_agg(const ushortx* __restrict__ hp, const int* __restrict__ rp,
                                             const int* __restrict__ csrc, const float* __restrict__ a_s,
                                             const float* __restrict__ a_d, const float* __restrict__ bias,
                                             ushortx* __restrict__ y, int H){
    int n = blockIdx.x, tid = threadIdx.x;
    int W = H * EMB;
    int beg = rp[n], deg = rp[n+1] - beg;

    __shared__ float sm[3], sden[3];
    __shared__ float sal[64*3];
    __shared__ int   ssrc[64];

    if (tid < 64){
        float adn[3];
#pragma unroll
        for (int h = 0; h < 3; h++) adn[h] = (h < H) ? a_d[n*H + h] : 0.f;
        float mx[3] = {-1e30f, -1e30f, -1e30f};
        for (int e = tid; e < deg; e += 64){
            int s = csrc[beg + e];
#pragma unroll
            for (int h = 0; h < 3; h++) if (h < H){
                float v = a_s[s*H + h] + adn[h];
                v = v > 0.f ? v : 0.2f*v;
                mx[h] = fmaxf(mx[h], v);
            }
        }
#pragma unroll
        for (int off = 32; off; off >>= 1){
#pragma unroll
            for (int h = 0; h < 3; h++) mx[h] = fmaxf(mx[h], __shfl_xor(mx[h], off));
        }
        float dn[3] = {0.f, 0.f, 0.f};
        for (int e = tid; e < deg; e += 64){
            int s = csrc[beg + e];
#pragma unroll
            for (int h = 0; h < 3; h++) if (h < H){
                float v = a_s[s*H + h] + adn[h];
                v = v > 0.f ? v : 0.2f*v;
                dn[h] += expf(v - mx[h]);
            }
        }
#pragma unroll
        for (int off = 32; off; off >>= 1){
#pragma unroll
            for (int h = 0; h < 3; h++) dn[h] += __shfl_xor(dn[h], off);
        }
        if (tid == 0){
#pragma unroll
            for (int h = 0; h < 3; h++){ sm[h] = mx[h]; sden[h] = dn[h]; }
        }
    }
    __syncthreads();

    float acc[10];
    int ci[10], hi[10];
#pragma unroll
    for (int i = 0; i < 10; i++){
        acc[i] = 0.f;
        ci[i] = tid + i*256;
        hi[i] = (ci[i] < W) ? (ci[i] / EMB) : 0;
    }

    for (int base = 0; base < deg; base += 64){
        int cnt = min(64, deg - base);
        if (tid < cnt) ssrc[tid] = csrc[beg + base + tid];
        if (tid < cnt*H){
            int e = tid / H, h = tid - e*H;
            int s = csrc[beg + base + e];
            float v = a_s[s*H + h] + a_d[n*H + h];
            v = v > 0.f ? v : 0.2f*v;
            sal[e*3 + h] = expf(v - sm[h]) / (sden[h] + 1e-16f);
        }
        __syncthreads();
        for (int e = 0; e < cnt; e++){
            const ushortx* rowp = hp + (size_t)ssrc[e]*W;
#pragma unroll
            for (int i = 0; i < 10; i++)
                if (ci[i] < W) acc[i] += sal[e*3 + hi[i]] * b2f(rowp[ci[i]]);
        }
        __syncthreads();
    }

#pragma unroll
    for (int i = 0; i < 10; i++)
        if (ci[i] < W) y[(size_t)n*W + ci[i]] = f2b(tanhf(acc[i] + bias[ci[i]]));
}

// ---------------- BatchNorm (batch stats) ----------------
__global__ void k_bnstat(const ushortx* __restrict__ y, float* __restrict__ psum,
                         float* __restrict__ psq, int W){
    int c = blockIdx.x*64 + (threadIdx.x & 63);
    int rl = threadIdx.x >> 6;   // 0..3
    int slice = blockIdx.y;      // 0..15
    if (c >= W) return;
    float s = 0.f, s2 = 0.f;
    for (int r = slice*4 + rl; r < NN; r += 64){
        float v = b2f(y[(size_t)r*W + c]);
        s += v; s2 += v*v;
    }
    atomicAdd(&psum[c], s);
    atomicAdd(&psq[c], s2);
}

__global__ void k_bnfin(const float* __restrict__ psum, const float* __restrict__ psq,
                        float* __restrict__ mu, float* __restrict__ istd, int W){
    int c = blockIdx.x*256 + threadIdx.x; if (c >= W) return;
    float m = psum[c] * (1.f/NN);
    float v = psq[c] * (1.f/NN) - m*m;
    mu[c] = m;
    istd[c] = 1.f / sqrtf(v + 1e-5f);
}

__global__ void k_bnapply(ushortx* __restrict__ y, const float* __restrict__ mu,
                          const float* __restrict__ istd, const float* __restrict__ gamma,
                          const float* __restrict__ beta, int W){
    int idx = blockIdx.x*256 + threadIdx.x;
    int total = NN * W / 4;
    if (idx >= total) return;
    int c = (idx % (W/4)) * 4;
    ushort4 u = *(ushort4*)(y + (size_t)idx*4);
    float4 v = make_float4(b2f(u.x), b2f(u.y), b2f(u.z), b2f(u.w));
    v.x = (v.x - mu[c+0]) * istd[c+0] * gamma[c+0] + beta[c+0];
    v.y = (v.y - mu[c+1]) * istd[c+1] * gamma[c+1] + beta[c+1];
    v.z = (v.z - mu[c+2]) * istd[c+2] * gamma[c+2] + beta[c+2];
    v.w = (v.w - mu[c+3]) * istd[c+3] * gamma[c+3] + beta[c+3];
    u.x = f2b(v.x); u.y = f2b(v.y); u.z = f2b(v.z); u.w = f2b(v.w);
    *(ushort4*)(y + (size_t)idx*4) = u;
}

// ---------------- pooling + MLP ----------------
__global__ void k_cnt(const int* __restrict__ batch, float* __restrict__ cnt){
    int n = blockIdx.x*256 + threadIdx.x; if (n >= NN) return;
    atomicAdd(&cnt[batch[n]], 1.f);
}

__global__ void k_pool(const ushortx* __restrict__ h, const int* __restrict__ batch,
                       float* __restrict__ pooled){
    int idx = blockIdx.x*256 + threadIdx.x; if (idx >= NN*EMB) return;
    int n = idx / EMB, c = idx - n*EMB;
    atomicAdd(&pooled[batch[n]*EMB + c], b2f(h[idx]));
}

__global__ __launch_bounds__(256) void k_mlp(const float* __restrict__ pooled, const float* __restrict__ cnt,
                                             const float* __restrict__ W1, const float* __restrict__ b1,
                                             const float* __restrict__ W2, const float* __restrict__ b2,
                                             float* __restrict__ out){
    __shared__ float p[EMB];
    __shared__ float hid[128];
    int g = blockIdx.x, tid = threadIdx.x;
    float ic = 1.f / fmaxf(cnt[g], 1.f);
    for (int c = tid; c < EMB; c += 256){
        float v = pooled[g*EMB + c] * ic;
        p[c] = v > 0.f ? v : 0.f;
    }
    __syncthreads();
    if (tid < 128){
        float s = b1[tid];
        for (int k = 0; k < EMB; k++) s += p[k] * W1[k*128 + tid];
        hid[tid] = tanhf(s);
    }
    __syncthreads();
    if (tid < 64){
        float s = b2[tid];
        for (int k = 0; k < 128; k++) s += hid[k] * W2[k*64 + tid];
        out[g*64 + tid] = s;
    }
}

// ---------------- launch ----------------
extern "C" void kernel_launch(void* const* d_in, const int* in_sizes, int n_in,
                              void* d_out, int out_size, void* d_ws, size_t ws_size,
                              hipStream_t stream) {
    (void)in_sizes; (void)n_in; (void)out_size;
    const float* x    = (const float*)d_in[0];
    const int*   ei   = (const int*)  d_in[1];
    const int*   batch= (const int*)  d_in[2];
    const float* tW   = (const float*)d_in[3];
    const float* tb   = (const float*)d_in[4];
    const float* W0   = (const float*)d_in[5];
    const float* as0  = (const float*)d_in[6];
    const float* ad0  = (const float*)d_in[7];
    const float* b0   = (const float*)d_in[8];
    const float* g0   = (const float*)d_in[9];
    const float* be0  = (const float*)d_in[10];
    const float* W1   = (const float*)d_in[11];
    const float* as1  = (const float*)d_in[12];
    const float* ad1  = (const float*)d_in[13];
    const float* b1   = (const float*)d_in[14];
    const float* g1   = (const float*)d_in[15];
    const float* be1  = (const float*)d_in[16];
    const float* W2   = (const float*)d_in[17];
    const float* as2  = (const float*)d_in[18];
    const float* ad2  = (const float*)d_in[19];
    const float* b2   = (const float*)d_in[20];
    const float* g2   = (const float*)d_in[21];
    const float* be2  = (const float*)d_in[22];
    const float* mW1  = (const float*)d_in[23];
    const float* mb1  = (const float*)d_in[24];
    const float* mW2  = (const float*)d_in[25];
    const float* mb2  = (const float*)d_in[26];
    float* outp = (float*)d_out;

    // workspace carve (256B aligned)
    size_t off = 0;
    auto carve = [&](size_t bytes) -> void* {
        void* p = (char*)d_ws + off;
        off = (off + bytes + 255) & ~(size_t)255;
        return p;
    };
    ushortx* hA  = (ushortx*)carve((size_t)NN*W3*2);   // 93.6 MB
    ushortx* hB  = (ushortx*)carve((size_t)NN*W3*2);   // 93.6 MB
    ushortx* Wb0 = (ushortx*)carve((size_t)(EMB*W3 + W3*W3 + W3*EMB)*2);  // 18.3 MB
    ushortx* Wb1 = Wb0 + (size_t)EMB*W3;
    ushortx* Wb2 = Wb1 + (size_t)W3*W3;
    float* a_s   = (float*)carve((size_t)NN*3*4);
    float* a_d   = (float*)carve((size_t)NN*3*4);
    float* psum  = (float*)carve((size_t)2*W3*4);   // psum + psq
    float* psq   = psum + W3;
    float* mu    = (float*)carve((size_t)W3*4);
    float* istd  = (float*)carve((size_t)W3*4);
    float* pooled= (float*)carve((size_t)(NGR*EMB + NGR)*4);
    float* cnt   = pooled + NGR*EMB;
    int*   deg   = (int*)carve((size_t)NN*4);       // reused as cursor
    int*   rp    = (int*)carve((size_t)(NN+1)*4);
    int*   csrc  = (int*)carve((size_t)ELP*4);

    // diagnostic guard: if workspace too small, do nothing (absmax will equal ref absmax)
    if (ws_size < off) return;

    // CSR build (same graph all layers)
    k_zero_i32<<<cdiv_i(NN,256),256,0,stream>>>(deg, NN);
    k_deg<<<cdiv_i(ELP,256),256,0,stream>>>(ei, deg);
    k_scan<<<1,1024,0,stream>>>(deg, rp);
    k_copy_i32<<<cdiv_i(NN,256),256,0,stream>>>(rp, deg, NN);
    k_fill<<<cdiv_i(ELP,256),256,0,stream>>>(ei, deg, csrc);

    // weights -> bf16
    k_castw<<<cdiv_i((long long)EMB*W3,256),256,0,stream>>>(W0, Wb0, EMB*W3);
    k_castw<<<cdiv_i((long long)W3*W3,256),256,0,stream>>>(W1, Wb1, W3*W3);
    k_castw<<<cdiv_i((long long)W3*EMB,256),256,0,stream>>>(W2, Wb2, W3*EMB);

    // h0
    k_build_h<<<cdiv_i((long long)NN*EMB,256),256,0,stream>>>(x, tW, tb, hA);

    struct Layer { const ushortx* W; const float* as; const float* ad; const float* b;
                   const float* g; const float* be; int H; int Kin; };
    Layer layers[3] = {
        {Wb0, as0, ad0, b0, g0, be0, 3, EMB},
        {Wb1, as1, ad1, b1, g1, be1, 3, W3},
        {Wb2, as2, ad2, b2, g2, be2, 1, W3},
    };

    for (int L = 0; L < 3; L++){
        Layer& ly = layers[L];
        int Wout = ly.H * EMB;
        // hp = h @ W
        dim3 gg(cdiv_i(Wout,128), cdiv_i(NN,128));
        k_gemm_bf16<<<gg,256,0,stream>>>(hA, ly.W, hB, NN, ly.Kin, Wout);
        // attention coefficients
        k_att<<<NN, ly.H*64, 0, stream>>>(hB, ly.as, ly.ad, a_s, a_d, ly.H);
        // softmax + aggregate + bias + tanh -> hA
        k_agg<<<NN,256,0,stream>>>(hB, rp, csrc, a_s, a_d, ly.b, hA, ly.H);
        // batchnorm
        k_zero_f32<<<cdiv_i(2*W3,256),256,0,stream>>>(psum, 2*W3);
        dim3 gs(cdiv_i(Wout,64), 16);
        k_bnstat<<<gs,256,0,stream>>>(hA, psum, psq, Wout);
        k_bnfin<<<cdiv_i(Wout,256),256,0,stream>>>(psum, psq, mu, istd, Wout);
        k_bnapply<<<cdiv_i((long long)NN*Wout/4,256),256,0,stream>>>(hA, mu, istd, ly.g, ly.be, Wout);
    }

    // pooling + MLP
    k_zero_f32<<<cdiv_i(NGR*EMB + NGR,256),256,0,stream>>>(pooled, NGR*EMB + NGR);
    k_cnt<<<cdiv_i(NN,256),256,0,stream>>>(batch, cnt);
    k_pool<<<cdiv_i((long long)NN*EMB,256),256,0,stream>>>(hA, batch, pooled);
    k_mlp<<<NGR,256,0,stream>>>(pooled, cnt, mW1, mb1, mW2, mb2, outp);
}

// Round 3
// 2074.356 us; speedup vs baseline: 3.2745x; 3.2745x over previous
//
#include <hip/hip_runtime.h>
#include <math.h>

#define NN   20000
#define EE   80000
#define ELP  100000   // EE + NN self loops
#define NGR  64
#define EMB  780
#define W3   2340
#define EMBP 800      // 780 padded to mult of 32 (K-chunk) ; 800*2B = 1600B, 16B-aligned rows
#define W3P  2368     // 2340 padded to mult of 32 ; 2368*2B = 4736B, 16B-aligned rows

static inline int cdiv_i(long long a, long long b){ return (int)((a + b - 1) / b); }

typedef _Float16 f16;
typedef _Float16 f16x2 __attribute__((ext_vector_type(2)));
typedef _Float16 f16x4 __attribute__((ext_vector_type(4)));
typedef _Float16 f16x8 __attribute__((ext_vector_type(8)));
typedef float    f32x4 __attribute__((ext_vector_type(4)));

// async global->LDS, 16B per lane; LDS dest = wave-uniform base + lane*16
__device__ __forceinline__ void async_ld16(const f16* g, f16* l){
    __builtin_amdgcn_global_load_lds(
        (const __attribute__((address_space(1))) unsigned int*)g,
        (__attribute__((address_space(3))) unsigned int*)l,
        16, 0, 0);
}

// ---------------- utility kernels ----------------
__global__ void k_zero_f32(float* p, int n){
    int i = blockIdx.x*256 + threadIdx.x; if (i < n) p[i] = 0.f;
}
__global__ void k_zero_i32(int* p, int n){
    int i = blockIdx.x*256 + threadIdx.x; if (i < n) p[i] = 0;
}
__global__ void k_copy_i32(const int* __restrict__ s, int* __restrict__ d, int n){
    int i = blockIdx.x*256 + threadIdx.x; if (i < n) d[i] = s[i];
}

// W [K,N] fp32 row-major -> Wt [N, KP] f16 row-major, pad cols (k in [K,KP)) zeroed
__global__ void k_transpose(const float* __restrict__ W, f16* __restrict__ Wt,
                            int K, int N, int KP){
    __shared__ float T[32][33];
    int n0 = blockIdx.x*32, k0 = blockIdx.y*32;
    int tx = threadIdx.x, ty = threadIdx.y;   // 32 x 8
#pragma unroll
    for (int r = 0; r < 4; r++){
        int k = k0 + ty + r*8;
        T[ty + r*8][tx] = (k < K && n0 + tx < N) ? W[(size_t)k*N + n0 + tx] : 0.f;
    }
    __syncthreads();
#pragma unroll
    for (int r = 0; r < 4; r++){
        int n = n0 + ty + r*8;
        int k = k0 + tx;
        if (n < N && k < KP) Wt[(size_t)n*KP + k] = (f16)T[tx][ty + r*8];
    }
}

// ---------------- h0 = [x[:, :768], x[:,768:772] @ time_W + time_b] (f16, stride EMBP) ----
__global__ void k_build_h(const float* __restrict__ x, const float* __restrict__ tW,
                          const float* __restrict__ tb, f16* __restrict__ h){
    int idx = blockIdx.x*256 + threadIdx.x;
    if (idx >= NN*EMBP) return;
    int n = idx / EMBP, c = idx - n*EMBP;
    const float* xr = x + (size_t)n*772;
    float v;
    if (c < 768) v = xr[c];
    else if (c < EMB){
        int j = c - 768;
        v = tb[j] + xr[768]*tW[j] + xr[769]*tW[12+j] + xr[770]*tW[24+j] + xr[771]*tW[36+j];
    } else v = 0.f;
    h[idx] = (f16)v;
}

// ---------------- CSR build (dst-sorted incoming edges) ----------------
__global__ void k_deg(const int* __restrict__ ei, int* __restrict__ deg){
    int k = blockIdx.x*256 + threadIdx.x; if (k >= ELP) return;
    int d = (k < EE) ? ei[EE + k] : (k - EE);
    atomicAdd(&deg[d], 1);
}

__global__ __launch_bounds__(1024) void k_scan(const int* __restrict__ deg, int* __restrict__ rp){
    __shared__ int buf[1024];
    __shared__ int carry;
    int tid = threadIdx.x;
    if (tid == 0){ carry = 0; rp[0] = 0; }
    __syncthreads();
    for (int base = 0; base < NN; base += 1024){
        int i = base + tid;
        int v = (i < NN) ? deg[i] : 0;
        buf[tid] = v; __syncthreads();
        for (int off = 1; off < 1024; off <<= 1){
            int t = (tid >= off) ? buf[tid-off] : 0;
            __syncthreads();
            buf[tid] += t;
            __syncthreads();
        }
        int incl = buf[tid];
        int tot  = buf[1023];
        if (i < NN) rp[i+1] = carry + incl;
        __syncthreads();
        if (tid == 0) carry += tot;
        __syncthreads();
    }
}

__global__ void k_fill(const int* __restrict__ ei, int* __restrict__ cursor, int* __restrict__ csrc){
    int k = blockIdx.x*256 + threadIdx.x; if (k >= ELP) return;
    int s, d;
    if (k < EE){ s = ei[k]; d = ei[EE + k]; } else { s = k - EE; d = s; }
    int pos = atomicAdd(&cursor[d], 1);
    csrc[pos] = s;
}

// ---------------- MFMA f16 GEMM: C[M,SN] = A[M,KP] @ Bt[N,KP]^T ----------------
// m97 structure: 128x128 tile, BK=32, 4 waves each 64x64 (4x4 of 16x16x32 MFMA),
// global_load_lds width-16 staging, row-clamped loads, guarded stores (pad cols zeroed).
__global__ __launch_bounds__(256) void k_gemm_mfma(const f16* __restrict__ A,
                                                   const f16* __restrict__ Bt,
                                                   f16* __restrict__ C,
                                                   int M, int N, int KP, int SN){
    __shared__ f16 As[128*32];
    __shared__ f16 Bs[128*32];
    int tid = threadIdx.x;
    int w = tid >> 6, lane = tid & 63;
    int m0 = blockIdx.y * 128, n0 = blockIdx.x * 128;

    int lrow = lane >> 2;        // 0..15
    int lko  = (lane & 3) * 8;   // k-offset: 0,8,16,24

    int i2a = w*2, i2b = w*2 + 1;   // staging instruction slots (16 rows each)
    const f16* gA0 = A  + (size_t)min(m0 + i2a*16 + lrow, M-1)*KP + lko;
    const f16* gA1 = A  + (size_t)min(m0 + i2b*16 + lrow, M-1)*KP + lko;
    const f16* gB0 = Bt + (size_t)min(n0 + i2a*16 + lrow, N-1)*KP + lko;
    const f16* gB1 = Bt + (size_t)min(n0 + i2b*16 + lrow, N-1)*KP + lko;
    f16* lA0 = &As[i2a*512]; f16* lA1 = &As[i2b*512];
    f16* lB0 = &Bs[i2a*512]; f16* lB1 = &Bs[i2b*512];

    f32x4 acc[4][4];
#pragma unroll
    for (int i = 0; i < 4; i++)
#pragma unroll
        for (int j = 0; j < 4; j++) acc[i][j] = (f32x4)0.f;

    int wm = (w & 1) * 64, wn = (w >> 1) * 64;
    int lq = lane >> 4, lm = lane & 15;

    for (int kk = 0; kk < KP; kk += 32){
        __syncthreads();
        async_ld16(gA0 + kk, lA0);
        async_ld16(gA1 + kk, lA1);
        async_ld16(gB0 + kk, lB0);
        async_ld16(gB1 + kk, lB1);
        __syncthreads();

        f16x8 aF[4], bF[4];
#pragma unroll
        for (int mi = 0; mi < 4; mi++)
            aF[mi] = *(const f16x8*)&As[(wm + mi*16 + lm)*32 + lq*8];
#pragma unroll
        for (int ni = 0; ni < 4; ni++)
            bF[ni] = *(const f16x8*)&Bs[(wn + ni*16 + lm)*32 + lq*8];
#pragma unroll
        for (int mi = 0; mi < 4; mi++)
#pragma unroll
            for (int ni = 0; ni < 4; ni++)
                acc[mi][ni] = __builtin_amdgcn_mfma_f32_16x16x32_f16(aF[mi], bF[ni], acc[mi][ni], 0, 0, 0);
    }

    // epilogue: C/D layout col=lane&15, row=(lane>>4)*4+reg
#pragma unroll
    for (int mi = 0; mi < 4; mi++){
#pragma unroll
        for (int ni = 0; ni < 4; ni++){
            int col = n0 + wn + ni*16 + lm;
            if (col < SN){
                int rbase = m0 + wm + mi*16 + lq*4;
#pragma unroll
                for (int r = 0; r < 4; r++){
                    int row = rbase + r;
                    if (row < M){
                        float v = (col < N) ? acc[mi][ni][r] : 0.f;
                        C[(size_t)row*SN + col] = (f16)v;
                    }
                }
            }
        }
    }
}

// ---------------- attention coefficients a_s[n,h], a_d[n,h] ----------------
__global__ void k_att(const f16* __restrict__ hp, const float* __restrict__ asrc,
                      const float* __restrict__ adst, float* __restrict__ a_s,
                      float* __restrict__ a_d, int H, int SP){
    int n = blockIdx.x;
    int wv = threadIdx.x >> 6, lane = threadIdx.x & 63;
    const f16* row = hp + (size_t)n*SP + wv*EMB;
    const float* pa = asrc + wv*EMB;
    const float* pd = adst + wv*EMB;
    float s = 0.f, d = 0.f;
    for (int c = lane; c < EMB; c += 64){ float v = (float)row[c]; s += v*pa[c]; d += v*pd[c]; }
#pragma unroll
    for (int off = 32; off; off >>= 1){ s += __shfl_xor(s, off); d += __shfl_xor(d, off); }
    if (lane == 0){ a_s[n*H + wv] = s; a_d[n*H + wv] = d; }
}

// ---------------- per-dst softmax + aggregation + bias + tanh (f16x2 cols) ----------------
__global__ __launch_bounds__(256) void k_agg(const f16* __restrict__ hp, const int* __restrict__ rp,
                                             const int* __restrict__ csrc, const float* __restrict__ a_s,
                                             const float* __restrict__ a_d, const float* __restrict__ bias,
                                             f16* __restrict__ y, int H, int SPhp, int SPy, int W){
    int n = blockIdx.x, tid = threadIdx.x;
    int beg = rp[n], deg = rp[n+1] - beg;

    __shared__ float sm[3], sden[3];
    __shared__ float sal[64*3];
    __shared__ int   ssrc[64];

    if (tid < 64){
        float adn[3];
#pragma unroll
        for (int h = 0; h < 3; h++) adn[h] = (h < H) ? a_d[n*H + h] : 0.f;
        float mx[3] = {-1e30f, -1e30f, -1e30f};
        for (int e = tid; e < deg; e += 64){
            int s = csrc[beg + e];
#pragma unroll
            for (int h = 0; h < 3; h++) if (h < H){
                float v = a_s[s*H + h] + adn[h];
                v = v > 0.f ? v : 0.2f*v;
                mx[h] = fmaxf(mx[h], v);
            }
        }
#pragma unroll
        for (int off = 32; off; off >>= 1){
#pragma unroll
            for (int h = 0; h < 3; h++) mx[h] = fmaxf(mx[h], __shfl_xor(mx[h], off));
        }
        float dn[3] = {0.f, 0.f, 0.f};
        for (int e = tid; e < deg; e += 64){
            int s = csrc[beg + e];
#pragma unroll
            for (int h = 0; h < 3; h++) if (h < H){
                float v = a_s[s*H + h] + adn[h];
                v = v > 0.f ? v : 0.2f*v;
                dn[h] += expf(v - mx[h]);
            }
        }
#pragma unroll
        for (int off = 32; off; off >>= 1){
#pragma unroll
            for (int h = 0; h < 3; h++) dn[h] += __shfl_xor(dn[h], off);
        }
        if (tid == 0){
#pragma unroll
            for (int h = 0; h < 3; h++){ sm[h] = mx[h]; sden[h] = dn[h]; }
        }
    }
    __syncthreads();

    float2 acc2[5];
    int c2[5], hh[5];
#pragma unroll
    for (int i = 0; i < 5; i++){
        acc2[i] = make_float2(0.f, 0.f);
        c2[i] = tid*2 + i*512;
        hh[i] = (c2[i] < W) ? (c2[i] / EMB) : 0;   // head boundaries are even; pairs never straddle
    }

    for (int base = 0; base < deg; base += 64){
        int cnt = min(64, deg - base);
        if (tid < cnt) ssrc[tid] = csrc[beg + base + tid];
        if (tid < cnt*H){
            int e = tid / H, h = tid - e*H;
            int s = csrc[beg + base + e];
            float v = a_s[s*H + h] + a_d[n*H + h];
            v = v > 0.f ? v : 0.2f*v;
            sal[e*3 + h] = expf(v - sm[h]) / (sden[h] + 1e-16f);
        }
        __syncthreads();
        for (int e = 0; e < cnt; e++){
            const f16* rowp = hp + (size_t)ssrc[e]*SPhp;
#pragma unroll
            for (int i = 0; i < 5; i++)
                if (c2[i] < W){
                    f16x2 v = *(const f16x2*)(rowp + c2[i]);
                    float al = sal[e*3 + hh[i]];
                    acc2[i].x += al * (float)v.x;
                    acc2[i].y += al * (float)v.y;
                }
        }
        __syncthreads();
    }

#pragma unroll
    for (int i = 0; i < 5; i++){
        int c = c2[i];
        if (c < SPy){
            f16x2 o;
            if (c < W){
                o.x = (f16)tanhf(acc2[i].x + bias[c]);
                o.y = (f16)tanhf(acc2[i].y + bias[c+1]);
            } else { o.x = (f16)0.f; o.y = (f16)0.f; }
            *(f16x2*)(y + (size_t)n*SPy + c) = o;
        }
    }
}

// ---------------- BatchNorm (batch stats) ----------------
__global__ void k_bnstat(const f16* __restrict__ y, float* __restrict__ psum,
                         float* __restrict__ psq, int W, int SP){
    int c = blockIdx.x*64 + (threadIdx.x & 63);
    int rl = threadIdx.x >> 6;   // 0..3
    int slice = blockIdx.y;      // 0..15
    if (c >= W) return;
    float s = 0.f, s2 = 0.f;
    for (int r = slice*4 + rl; r < NN; r += 64){
        float v = (float)y[(size_t)r*SP + c];
        s += v; s2 += v*v;
    }
    atomicAdd(&psum[c], s);
    atomicAdd(&psq[c], s2);
}

__global__ void k_bnfin(const float* __restrict__ psum, const float* __restrict__ psq,
                        float* __restrict__ mu, float* __restrict__ istd, int W){
    int c = blockIdx.x*256 + threadIdx.x; if (c >= W) return;
    float m = psum[c] * (1.f/NN);
    float v = psq[c] * (1.f/NN) - m*m;
    mu[c] = m;
    istd[c] = 1.f / sqrtf(v + 1e-5f);
}

__global__ void k_bnapply(f16* __restrict__ y, const float* __restrict__ mu,
                          const float* __restrict__ istd, const float* __restrict__ gamma,
                          const float* __restrict__ beta, int W, int SP){
    int idx = blockIdx.x*256 + threadIdx.x;
    int w4 = W >> 2;
    if (idx >= NN * w4) return;
    int row = idx / w4;
    int c = (idx - row*w4) * 4;
    f16* p = y + (size_t)row*SP + c;
    f16x4 u = *(f16x4*)p;
#pragma unroll
    for (int j = 0; j < 4; j++){
        float v = ((float)u[j] - mu[c+j]) * istd[c+j] * gamma[c+j] + beta[c+j];
        u[j] = (f16)v;
    }
    *(f16x4*)p = u;
}

// ---------------- pooling + MLP ----------------
__global__ void k_cnt(const int* __restrict__ batch, float* __restrict__ cnt){
    int n = blockIdx.x*256 + threadIdx.x; if (n >= NN) return;
    atomicAdd(&cnt[batch[n]], 1.f);
}

__global__ void k_pool(const f16* __restrict__ h, const int* __restrict__ batch,
                       float* __restrict__ pooled){
    int idx = blockIdx.x*256 + threadIdx.x; if (idx >= NN*EMB) return;
    int n = idx / EMB, c = idx - n*EMB;
    atomicAdd(&pooled[batch[n]*EMB + c], (float)h[(size_t)n*EMBP + c]);
}

__global__ __launch_bounds__(256) void k_mlp(const float* __restrict__ pooled, const float* __restrict__ cnt,
                                             const float* __restrict__ W1, const float* __restrict__ b1,
                                             const float* __restrict__ W2, const float* __restrict__ b2,
                                             float* __restrict__ out){
    __shared__ float p[EMB];
    __shared__ float hid[128];
    int g = blockIdx.x, tid = threadIdx.x;
    float ic = 1.f / fmaxf(cnt[g], 1.f);
    for (int c = tid; c < EMB; c += 256){
        float v = pooled[g*EMB + c] * ic;
        p[c] = v > 0.f ? v : 0.f;
    }
    __syncthreads();
    if (tid < 128){
        float s = b1[tid];
        for (int k = 0; k < EMB; k++) s += p[k] * W1[k*128 + tid];
        hid[tid] = tanhf(s);
    }
    __syncthreads();
    if (tid < 64){
        float s = b2[tid];
        for (int k = 0; k < 128; k++) s += hid[k] * W2[k*64 + tid];
        out[g*64 + tid] = s;
    }
}

// ---------------- launch ----------------
extern "C" void kernel_launch(void* const* d_in, const int* in_sizes, int n_in,
                              void* d_out, int out_size, void* d_ws, size_t ws_size,
                              hipStream_t stream) {
    (void)in_sizes; (void)n_in; (void)out_size;
    const float* x    = (const float*)d_in[0];
    const int*   ei   = (const int*)  d_in[1];
    const int*   batch= (const int*)  d_in[2];
    const float* tW   = (const float*)d_in[3];
    const float* tb   = (const float*)d_in[4];
    const float* W0   = (const float*)d_in[5];
    const float* as0  = (const float*)d_in[6];
    const float* ad0  = (const float*)d_in[7];
    const float* b0   = (const float*)d_in[8];
    const float* g0   = (const float*)d_in[9];
    const float* be0  = (const float*)d_in[10];
    const float* W1   = (const float*)d_in[11];
    const float* as1  = (const float*)d_in[12];
    const float* ad1  = (const float*)d_in[13];
    const float* b1   = (const float*)d_in[14];
    const float* g1   = (const float*)d_in[15];
    const float* be1  = (const float*)d_in[16];
    const float* W2   = (const float*)d_in[17];
    const float* as2  = (const float*)d_in[18];
    const float* ad2  = (const float*)d_in[19];
    const float* b2   = (const float*)d_in[20];
    const float* g2   = (const float*)d_in[21];
    const float* be2  = (const float*)d_in[22];
    const float* mW1  = (const float*)d_in[23];
    const float* mb1  = (const float*)d_in[24];
    const float* mW2  = (const float*)d_in[25];
    const float* mb2  = (const float*)d_in[26];
    float* outp = (float*)d_out;

    // workspace carve (256B aligned). Budget ~201.8 MB (proven ws >= 206.7 MB).
    size_t off = 0;
    auto carve = [&](size_t bytes) -> void* {
        void* p = (char*)d_ws + off;
        off = (off + bytes + 255) & ~(size_t)255;
        return p;
    };
    f16* big1 = (f16*)carve((size_t)NN*W3P*2);          // 94.72 MB: h0/h1/h2/h_final
    f16* big2 = (f16*)carve((size_t)NN*W3P*2);          // 94.72 MB: hp per layer
    f16* Wt   = (f16*)carve((size_t)W3*W3P*2);          // 11.08 MB shared transposed-weight scratch
    float* a_s   = (float*)carve((size_t)NN*3*4);
    float* a_d   = (float*)carve((size_t)NN*3*4);
    float* psum  = (float*)carve((size_t)2*W3*4);
    float* psq   = psum + W3;
    float* mu    = (float*)carve((size_t)W3*4);
    float* istd  = (float*)carve((size_t)W3*4);
    float* pooled= (float*)carve((size_t)(NGR*EMB + NGR)*4);
    float* cnt   = pooled + NGR*EMB;
    int*   deg   = (int*)carve((size_t)NN*4);           // reused as cursor
    int*   rp    = (int*)carve((size_t)(NN+1)*4);
    int*   csrc  = (int*)carve((size_t)ELP*4);

    if (ws_size < off) return;   // diagnostic guard

    // CSR build (same graph all layers)
    k_zero_i32<<<cdiv_i(NN,256),256,0,stream>>>(deg, NN);
    k_deg<<<cdiv_i(ELP,256),256,0,stream>>>(ei, deg);
    k_scan<<<1,1024,0,stream>>>(deg, rp);
    k_copy_i32<<<cdiv_i(NN,256),256,0,stream>>>(rp, deg, NN);
    k_fill<<<cdiv_i(ELP,256),256,0,stream>>>(ei, deg, csrc);

    // h0 (f16, stride EMBP, pad cols zero)
    k_build_h<<<cdiv_i((long long)NN*EMBP,256),256,0,stream>>>(x, tW, tb, big1);

    struct Layer { const float* W; const float* as; const float* ad; const float* b;
                   const float* g; const float* be; int H; int K; int KP; };
    Layer layers[3] = {
        {W0, as0, ad0, b0, g0, be0, 3, EMB, EMBP},
        {W1, as1, ad1, b1, g1, be1, 3, W3,  W3P },
        {W2, as2, ad2, b2, g2, be2, 1, W3,  W3P },
    };

    for (int L = 0; L < 3; L++){
        Layer& ly = layers[L];
        int Wout  = ly.H * EMB;                 // 2340 / 2340 / 780
        int SPout = (Wout == W3) ? W3P : EMBP;  // 2368 / 2368 / 800

        // Wt[N=Wout][KP] <- transpose of W[K][N]
        dim3 tg(cdiv_i(Wout,32), cdiv_i(ly.KP,32));
        k_transpose<<<tg, dim3(32,8), 0, stream>>>(ly.W, Wt, ly.K, Wout, ly.KP);

        // hp = h @ W  via f16 MFMA
        dim3 gg(cdiv_i(Wout,128), cdiv_i(NN,128));
        k_gemm_mfma<<<gg, 256, 0, stream>>>(big1, Wt, big2, NN, Wout, ly.KP, SPout);

        // attention coefficients
        k_att<<<NN, ly.H*64, 0, stream>>>(big2, ly.as, ly.ad, a_s, a_d, ly.H, SPout);

        // softmax + aggregate + bias + tanh -> big1 (y, stride SPout, pads zeroed)
        k_agg<<<NN,256,0,stream>>>(big2, rp, csrc, a_s, a_d, ly.b, big1, ly.H, SPout, SPout, Wout);

        // batchnorm (stats fp32, apply in-place on f16 y)
        k_zero_f32<<<cdiv_i(2*W3,256),256,0,stream>>>(psum, 2*W3);
        dim3 gs(cdiv_i(Wout,64), 16);
        k_bnstat<<<gs,256,0,stream>>>(big1, psum, psq, Wout, SPout);
        k_bnfin<<<cdiv_i(Wout,256),256,0,stream>>>(psum, psq, mu, istd, Wout);
        k_bnapply<<<cdiv_i((long long)NN*(Wout/4),256),256,0,stream>>>(big1, mu, istd, ly.g, ly.be, Wout, SPout);
    }

    // pooling + MLP
    k_zero_f32<<<cdiv_i(NGR*EMB + NGR,256),256,0,stream>>>(pooled, NGR*EMB + NGR);
    k_cnt<<<cdiv_i(NN,256),256,0,stream>>>(batch, cnt);
    k_pool<<<cdiv_i((long long)NN*EMB,256),256,0,stream>>>(big1, batch, pooled);
    k_mlp<<<NGR,256,0,stream>>>(pooled, cnt, mW1, mb1, mW2, mb2, outp);
}